// Round 1
// baseline (836.178 us; speedup 1.0000x reference)
//
#include <hip/hip_runtime.h>
#include <cstdint>

#define FIN 512
#define HID 16
#define NCLS 40

// ---------------- utility kernels ----------------

__global__ void zero2_kernel(int* __restrict__ a, int* __restrict__ b, int n) {
    int i = blockIdx.x * blockDim.x + threadIdx.x;
    if (i < n) { a[i] = 0; b[i] = 0; }
}

// histogram: deg over src (for norm), cnt over tgt (for CSR)
__global__ void hist_kernel(const int* __restrict__ ei, int E,
                            int* __restrict__ deg, int* __restrict__ cnt) {
    int i = blockIdx.x * blockDim.x + threadIdx.x;
    int stride = gridDim.x * blockDim.x;
    for (; i < E; i += stride) {
        atomicAdd(&deg[ei[i]], 1);        // src
        atomicAdd(&cnt[ei[E + i]], 1);    // tgt
    }
}

__global__ void dinv_kernel(const int* __restrict__ deg, float* __restrict__ dinv, int n) {
    int i = blockIdx.x * blockDim.x + threadIdx.x;
    if (i < n) dinv[i] = rsqrtf((float)(deg[i] + 1));   // +1 self loop
}

// ---------------- scan (exclusive prefix sum over cnt -> row_ptr) ----------------

__global__ void scanA_kernel(const int* __restrict__ cnt, int* __restrict__ row_ptr,
                             int* __restrict__ bsum, int n) {
    __shared__ int tmp[256];
    int t = threadIdx.x;
    int i = blockIdx.x * 256 + t;
    int v = (i < n) ? cnt[i] : 0;
    tmp[t] = v;
    __syncthreads();
    for (int off = 1; off < 256; off <<= 1) {
        int a = (t >= off) ? tmp[t - off] : 0;
        __syncthreads();
        tmp[t] += a;
        __syncthreads();
    }
    if (i < n) row_ptr[i] = tmp[t] - v;          // block-local exclusive
    if (t == 255) bsum[blockIdx.x] = tmp[255];   // block total
}

__global__ void scanB_kernel(int* __restrict__ bsum, int nb) {
    __shared__ int tmp[512];
    int t = threadIdx.x;
    int v = (t < nb) ? bsum[t] : 0;
    tmp[t] = v;
    __syncthreads();
    for (int off = 1; off < 512; off <<= 1) {
        int a = (t >= off) ? tmp[t - off] : 0;
        __syncthreads();
        tmp[t] += a;
        __syncthreads();
    }
    if (t < nb) bsum[t] = tmp[t] - v;            // exclusive block offsets
}

__global__ void scanC_kernel(int* __restrict__ row_ptr, int* __restrict__ cursor,
                             const int* __restrict__ bsum, int n, int E) {
    int i = blockIdx.x * blockDim.x + threadIdx.x;
    if (i < n) {
        int v = row_ptr[i] + bsum[blockIdx.x];
        row_ptr[i] = v;
        cursor[i] = v;
    }
    if (i == 0) row_ptr[n] = E;
}

// ---------------- scatter edges into CSR (by target), fused norm ----------------

__global__ void scatter_kernel(const int* __restrict__ ei, int E,
                               const float* __restrict__ dinv,
                               int* __restrict__ cursor, int2* __restrict__ edges) {
    int i = blockIdx.x * blockDim.x + threadIdx.x;
    int stride = gridDim.x * blockDim.x;
    for (; i < E; i += stride) {
        int s = ei[i], t = ei[E + i];
        float nrm = dinv[s] * dinv[t];
        int pos = atomicAdd(&cursor[t], 1);
        edges[pos] = make_int2(s, __float_as_int(nrm));
    }
}

// ---------------- linear layer 1: h1 = X @ W1 + b1 ----------------

__global__ void linear1_kernel(const float* __restrict__ x, const float* __restrict__ w1,
                               const float* __restrict__ b1, float* __restrict__ h1, int n) {
    __shared__ float wl[FIN * HID];   // 32 KB
    __shared__ float bl[HID];
    for (int i = threadIdx.x; i < FIN * HID; i += blockDim.x) wl[i] = w1[i];
    if (threadIdx.x < HID) bl[threadIdx.x] = b1[threadIdx.x];
    __syncthreads();
    int row = blockIdx.x * blockDim.x + threadIdx.x;
    if (row >= n) return;
    const float4* xr = (const float4*)(x + (size_t)row * FIN);
    float acc[HID];
#pragma unroll
    for (int c = 0; c < HID; ++c) acc[c] = bl[c];
    for (int k4 = 0; k4 < FIN / 4; ++k4) {
        float4 xv = xr[k4];
        const float* wr = &wl[k4 * 4 * HID];
#pragma unroll
        for (int c = 0; c < HID; ++c) acc[c] = fmaf(xv.x, wr[c], acc[c]);
#pragma unroll
        for (int c = 0; c < HID; ++c) acc[c] = fmaf(xv.y, wr[HID + c], acc[c]);
#pragma unroll
        for (int c = 0; c < HID; ++c) acc[c] = fmaf(xv.z, wr[2 * HID + c], acc[c]);
#pragma unroll
        for (int c = 0; c < HID; ++c) acc[c] = fmaf(xv.w, wr[3 * HID + c], acc[c]);
    }
    float4* hr = (float4*)(h1 + (size_t)row * HID);
    hr[0] = make_float4(acc[0], acc[1], acc[2], acc[3]);
    hr[1] = make_float4(acc[4], acc[5], acc[6], acc[7]);
    hr[2] = make_float4(acc[8], acc[9], acc[10], acc[11]);
    hr[3] = make_float4(acc[12], acc[13], acc[14], acc[15]);
}

// ---------------- pull aggregation (16 lanes per node, lane = channel) ----------------
// out[t][c] = dinv[t]^2 * in[t][c] + sum_{e: tgt==t} norm_e * in[src_e][c]
// optional relu; optional rowsum[t] = dinv[t]^2 + sum norm_e (for layer-2 bias)

__global__ void agg_kernel(const float* __restrict__ in, const int2* __restrict__ edges,
                           const int* __restrict__ row_ptr, const float* __restrict__ dinv,
                           float* __restrict__ out, float* __restrict__ rowsum,
                           int n, int do_relu) {
    int gid = blockIdx.x * blockDim.x + threadIdx.x;
    int node = gid >> 4;
    int lane = gid & 15;
    if (node >= n) return;
    float dv = dinv[node];
    float self = dv * dv;
    float acc = self * in[(size_t)node * HID + lane];
    float rs = self;
    int beg = row_ptr[node], end = row_ptr[node + 1];
#pragma unroll 4
    for (int i = beg; i < end; ++i) {
        int2 rec = edges[i];
        float nrm = __int_as_float(rec.y);
        acc = fmaf(nrm, in[(size_t)rec.x * HID + lane], acc);
        rs += nrm;
    }
    if (do_relu) acc = fmaxf(acc, 0.0f);
    out[(size_t)node * HID + lane] = acc;
    if (rowsum != nullptr && lane == 0) rowsum[node] = rs;
}

// ---------------- final: out = (q @ W2) + rowsum*b2, then log_softmax ----------------

__global__ void final_kernel(const float* __restrict__ q, const float* __restrict__ rowsum,
                             const float* __restrict__ w2, const float* __restrict__ b2,
                             float* __restrict__ out, int n) {
    __shared__ float wl[HID * NCLS];
    __shared__ float bl[NCLS];
    for (int i = threadIdx.x; i < HID * NCLS; i += blockDim.x) wl[i] = w2[i];
    if (threadIdx.x < NCLS) bl[threadIdx.x] = b2[threadIdx.x];
    __syncthreads();
    int node = blockIdx.x * blockDim.x + threadIdx.x;
    if (node >= n) return;
    float h[HID];
#pragma unroll
    for (int j = 0; j < HID; ++j) h[j] = q[(size_t)node * HID + j];
    float rs = rowsum[node];
    float z[NCLS];
#pragma unroll
    for (int c = 0; c < NCLS; ++c) {
        float s = rs * bl[c];
#pragma unroll
        for (int j = 0; j < HID; ++j) s = fmaf(h[j], wl[j * NCLS + c], s);
        z[c] = s;
    }
    float m = z[0];
#pragma unroll
    for (int c = 1; c < NCLS; ++c) m = fmaxf(m, z[c]);
    float se = 0.0f;
#pragma unroll
    for (int c = 0; c < NCLS; ++c) se += expf(z[c] - m);
    float lse = m + logf(se);
    float* orow = out + (size_t)node * NCLS;
#pragma unroll
    for (int c = 0; c < NCLS; ++c) orow[c] = z[c] - lse;
}

// ---------------- launch ----------------

extern "C" void kernel_launch(void* const* d_in, const int* in_sizes, int n_in,
                              void* d_out, int out_size, void* d_ws, size_t ws_size,
                              hipStream_t stream) {
    const float* x  = (const float*)d_in[0];
    const int*   ei = (const int*)d_in[1];
    const float* w1 = (const float*)d_in[2];
    const float* b1 = (const float*)d_in[3];
    const float* w2 = (const float*)d_in[4];
    const float* b2 = (const float*)d_in[5];
    float* out = (float*)d_out;

    int N = in_sizes[0] / FIN;     // 100000
    int E = in_sizes[1] / 2;       // 3200000

    // workspace carve-up (256B-aligned chunks)
    char* p = (char*)d_ws;
    auto alloc = [&](size_t bytes) -> char* {
        char* r = p;
        p += (bytes + 255) / 256 * 256;
        return r;
    };
    int*   deg     = (int*)alloc((size_t)N * 4);
    int*   cnt     = (int*)alloc((size_t)N * 4);          // reused as cursor
    int*   row_ptr = (int*)alloc((size_t)(N + 1) * 4);
    int*   bsum    = (int*)alloc(512 * 4);
    float* dinv    = (float*)alloc((size_t)N * 4);
    int2*  edges   = (int2*)alloc((size_t)E * 8);
    float* h1      = (float*)alloc((size_t)N * HID * 4);  // reused as q after agg1
    float* g       = (float*)alloc((size_t)N * HID * 4);
    float* rowsum  = (float*)alloc((size_t)N * 4);

    int nb = (N + 255) / 256;          // 391 (must be <= 512 for scanB)

    zero2_kernel<<<nb, 256, 0, stream>>>(deg, cnt, N);
    hist_kernel<<<2048, 256, 0, stream>>>(ei, E, deg, cnt);
    dinv_kernel<<<nb, 256, 0, stream>>>(deg, dinv, N);
    scanA_kernel<<<nb, 256, 0, stream>>>(cnt, row_ptr, bsum, N);
    scanB_kernel<<<1, 512, 0, stream>>>(bsum, nb);
    scanC_kernel<<<nb, 256, 0, stream>>>(row_ptr, cnt, bsum, N, E);
    scatter_kernel<<<2048, 256, 0, stream>>>(ei, E, dinv, cnt, edges);
    linear1_kernel<<<nb, 256, 0, stream>>>(x, w1, b1, h1, N);
    agg_kernel<<<(N * 16 + 255) / 256, 256, 0, stream>>>(h1, edges, row_ptr, dinv, g, rowsum, N, 1);
    agg_kernel<<<(N * 16 + 255) / 256, 256, 0, stream>>>(g, edges, row_ptr, dinv, h1, nullptr, N, 0);
    final_kernel<<<nb, 256, 0, stream>>>(h1, rowsum, w2, b2, out, N);
}

// Round 2
// 595.965 us; speedup vs baseline: 1.4031x; 1.4031x over previous
//
#include <hip/hip_runtime.h>
#include <cstdint>

#define FIN 512
#define HID 16
#define NCLS 40
#define SHIFT 8          // 256 nodes per coarse bucket
#define NBCAP 512        // LDS capacity for bucket count (nb = 391 for N=100000)
#define NBLK 512         // blocks for count/scatter (must match between the two)

// ---------------- coarse count: per-block LDS histograms over buckets ----------------

__global__ void count_kernel(const int* __restrict__ ei, int E, int nb,
                             int* __restrict__ hist_src_g, int* __restrict__ hist_tgt_g) {
    __shared__ int hs[NBCAP], ht[NBCAP];
    for (int j = threadIdx.x; j < NBCAP; j += 256) { hs[j] = 0; ht[j] = 0; }
    __syncthreads();
    for (int i = blockIdx.x * 256 + threadIdx.x; i < E; i += NBLK * 256) {
        atomicAdd(&hs[ei[i] >> SHIFT], 1);        // src bucket
        atomicAdd(&ht[ei[E + i] >> SHIFT], 1);    // tgt bucket
    }
    __syncthreads();
    int base = blockIdx.x * NBCAP;
    for (int j = threadIdx.x; j < NBCAP; j += 256) {
        hist_src_g[base + j] = hs[j];
        hist_tgt_g[base + j] = ht[j];
    }
}

// ---------------- column scan: per-bucket exclusive scan over blocks ----------------
// grid (nb, 2); block 512 threads; converts hist[blk][b] -> exclusive scan down the
// column, and emits bucket totals.

__global__ void colscan_kernel(int* __restrict__ hist_src_g, int* __restrict__ hist_tgt_g,
                               int* __restrict__ btot) {
    __shared__ int tmp[NBLK];
    int b = blockIdx.x;
    int* h = blockIdx.y ? hist_tgt_g : hist_src_g;
    int t = threadIdx.x;
    int v = h[t * NBCAP + b];
    tmp[t] = v;
    __syncthreads();
    for (int off = 1; off < NBLK; off <<= 1) {
        int a = (t >= off) ? tmp[t - off] : 0;
        __syncthreads();
        tmp[t] += a;
        __syncthreads();
    }
    h[t * NBCAP + b] = tmp[t] - v;
    if (t == NBLK - 1) btot[blockIdx.y * NBCAP + b] = tmp[NBLK - 1];
}

// ---------------- bucket scan: exclusive scan of bucket totals ----------------

__global__ void bucketscan_kernel(const int* __restrict__ btot, int nb,
                                  int* __restrict__ src_base, int* __restrict__ tgt_base,
                                  int* __restrict__ row_ptr, int N, int E) {
    __shared__ int tmp[512];
    int t = threadIdx.x;
    int v = (t < nb) ? btot[t] : 0;
    tmp[t] = v;
    __syncthreads();
    for (int off = 1; off < 512; off <<= 1) {
        int a = (t >= off) ? tmp[t - off] : 0;
        __syncthreads();
        tmp[t] += a;
        __syncthreads();
    }
    if (t < nb) src_base[t] = tmp[t] - v;
    __syncthreads();
    int v2 = (t < nb) ? btot[NBCAP + t] : 0;
    tmp[t] = v2;
    __syncthreads();
    for (int off = 1; off < 512; off <<= 1) {
        int a = (t >= off) ? tmp[t - off] : 0;
        __syncthreads();
        tmp[t] += a;
        __syncthreads();
    }
    if (t < nb) tgt_base[t] = tmp[t] - v2;
    if (t == 0) { src_base[nb] = E; tgt_base[nb] = E; row_ptr[N] = E; }
}

// ---------------- coarse scatter: LDS cursors, no global atomics ----------------
// tmp_src[pos] = low 8 bits of src (bucket implied by position)
// tmp_tgt[pos] = (tgt&255)<<17 | src   (src < 2^17)

__global__ void scatter_kernel(const int* __restrict__ ei, int E, int nb,
                               const int* __restrict__ hist_src_g,
                               const int* __restrict__ hist_tgt_g,
                               const int* __restrict__ src_base,
                               const int* __restrict__ tgt_base,
                               unsigned char* __restrict__ tmp_src,
                               unsigned int* __restrict__ tmp_tgt) {
    __shared__ int cs[NBCAP], ct[NBCAP];
    int blk = blockIdx.x;
    for (int j = threadIdx.x; j < nb; j += 256) {
        cs[j] = src_base[j] + hist_src_g[blk * NBCAP + j];
        ct[j] = tgt_base[j] + hist_tgt_g[blk * NBCAP + j];
    }
    __syncthreads();
    for (int i = blk * 256 + threadIdx.x; i < E; i += NBLK * 256) {
        int s = ei[i], tg = ei[E + i];
        int ps = atomicAdd(&cs[s >> SHIFT], 1);
        tmp_src[ps] = (unsigned char)(s & 255);
        int pt = atomicAdd(&ct[tg >> SHIFT], 1);
        tmp_tgt[pt] = ((unsigned int)(tg & 255) << 17) | (unsigned int)s;
    }
}

// ---------------- fine: per-bucket deg count -> dinv ----------------

__global__ void finedeg_kernel(const unsigned char* __restrict__ tmp_src,
                               const int* __restrict__ src_base,
                               float* __restrict__ dinv, int N) {
    __shared__ int hist[256];
    int b = blockIdx.x;
    int t = threadIdx.x;
    hist[t] = 0;
    __syncthreads();
    int beg = src_base[b], end = src_base[b + 1];
    for (int i = beg + t; i < end; i += 256)
        atomicAdd(&hist[tmp_src[i]], 1);
    __syncthreads();
    int node = b * 256 + t;
    if (node < N) dinv[node] = rsqrtf((float)(hist[t] + 1));   // +1 self loop
}

// ---------------- fine: per-bucket CSR build (row_ptr + edges=src only) ----------------

__global__ void finecsr_kernel(const unsigned int* __restrict__ tmp_tgt,
                               const int* __restrict__ tgt_base,
                               int* __restrict__ row_ptr, int* __restrict__ edges, int N) {
    __shared__ int hist[256];
    __shared__ int scan[256];
    int b = blockIdx.x;
    int t = threadIdx.x;
    hist[t] = 0;
    __syncthreads();
    int beg = tgt_base[b], end = tgt_base[b + 1];
    for (int i = beg + t; i < end; i += 256)
        atomicAdd(&hist[tmp_tgt[i] >> 17], 1);
    __syncthreads();
    int v = hist[t];
    scan[t] = v;
    __syncthreads();
    for (int off = 1; off < 256; off <<= 1) {
        int a = (t >= off) ? scan[t - off] : 0;
        __syncthreads();
        scan[t] += a;
        __syncthreads();
    }
    int ex = scan[t] - v;       // exclusive offset within bucket
    int node = b * 256 + t;
    if (node < N) row_ptr[node] = beg + ex;
    hist[t] = ex;               // reuse as cursor
    __syncthreads();
    for (int i = beg + t; i < end; i += 256) {
        unsigned int w = tmp_tgt[i];
        int tl = (int)(w >> 17);
        int src = (int)(w & 0x1FFFF);
        int pos = beg + atomicAdd(&hist[tl], 1);
        edges[pos] = src;
    }
}

// ---------------- linear layer 1: h1 = X @ W1 + b1 ----------------

__global__ void linear1_kernel(const float* __restrict__ x, const float* __restrict__ w1,
                               const float* __restrict__ b1, float* __restrict__ h1, int n) {
    __shared__ float wl[FIN * HID];   // 32 KB
    __shared__ float bl[HID];
    for (int i = threadIdx.x; i < FIN * HID; i += blockDim.x) wl[i] = w1[i];
    if (threadIdx.x < HID) bl[threadIdx.x] = b1[threadIdx.x];
    __syncthreads();
    int row = blockIdx.x * blockDim.x + threadIdx.x;
    if (row >= n) return;
    const float4* xr = (const float4*)(x + (size_t)row * FIN);
    float acc[HID];
#pragma unroll
    for (int c = 0; c < HID; ++c) acc[c] = bl[c];
    for (int k4 = 0; k4 < FIN / 4; ++k4) {
        float4 xv = xr[k4];
        const float* wr = &wl[k4 * 4 * HID];
#pragma unroll
        for (int c = 0; c < HID; ++c) acc[c] = fmaf(xv.x, wr[c], acc[c]);
#pragma unroll
        for (int c = 0; c < HID; ++c) acc[c] = fmaf(xv.y, wr[HID + c], acc[c]);
#pragma unroll
        for (int c = 0; c < HID; ++c) acc[c] = fmaf(xv.z, wr[2 * HID + c], acc[c]);
#pragma unroll
        for (int c = 0; c < HID; ++c) acc[c] = fmaf(xv.w, wr[3 * HID + c], acc[c]);
    }
    float4* hr = (float4*)(h1 + (size_t)row * HID);
    hr[0] = make_float4(acc[0], acc[1], acc[2], acc[3]);
    hr[1] = make_float4(acc[4], acc[5], acc[6], acc[7]);
    hr[2] = make_float4(acc[8], acc[9], acc[10], acc[11]);
    hr[3] = make_float4(acc[12], acc[13], acc[14], acc[15]);
}

// ---------------- pull aggregation (16 lanes per node, lane = channel) ----------------
// out[t][c] = dinv[t]^2 * in[t][c] + sum_{e: tgt==t} dinv[src]*dinv[t] * in[src][c]

__global__ void agg_kernel(const float* __restrict__ in, const int* __restrict__ edges,
                           const int* __restrict__ row_ptr, const float* __restrict__ dinv,
                           float* __restrict__ out, float* __restrict__ rowsum,
                           int n, int do_relu) {
    int gid = blockIdx.x * blockDim.x + threadIdx.x;
    int node = gid >> 4;
    int lane = gid & 15;
    if (node >= n) return;
    float dv = dinv[node];
    float self = dv * dv;
    float acc = self * in[(size_t)node * HID + lane];
    float rs = self;
    int beg = row_ptr[node], end = row_ptr[node + 1];
#pragma unroll 4
    for (int i = beg; i < end; ++i) {
        int src = edges[i];
        float nrm = dinv[src] * dv;
        acc = fmaf(nrm, in[(size_t)src * HID + lane], acc);
        rs += nrm;
    }
    if (do_relu) acc = fmaxf(acc, 0.0f);
    out[(size_t)node * HID + lane] = acc;
    if (rowsum != nullptr && lane == 0) rowsum[node] = rs;
}

// ---------------- final: out = (q @ W2) + rowsum*b2, then log_softmax ----------------

__global__ void final_kernel(const float* __restrict__ q, const float* __restrict__ rowsum,
                             const float* __restrict__ w2, const float* __restrict__ b2,
                             float* __restrict__ out, int n) {
    __shared__ float wl[HID * NCLS];
    __shared__ float bl[NCLS];
    for (int i = threadIdx.x; i < HID * NCLS; i += blockDim.x) wl[i] = w2[i];
    if (threadIdx.x < NCLS) bl[threadIdx.x] = b2[threadIdx.x];
    __syncthreads();
    int node = blockIdx.x * blockDim.x + threadIdx.x;
    if (node >= n) return;
    float h[HID];
#pragma unroll
    for (int j = 0; j < HID; ++j) h[j] = q[(size_t)node * HID + j];
    float rs = rowsum[node];
    float z[NCLS];
#pragma unroll
    for (int c = 0; c < NCLS; ++c) {
        float s = rs * bl[c];
#pragma unroll
        for (int j = 0; j < HID; ++j) s = fmaf(h[j], wl[j * NCLS + c], s);
        z[c] = s;
    }
    float m = z[0];
#pragma unroll
    for (int c = 1; c < NCLS; ++c) m = fmaxf(m, z[c]);
    float se = 0.0f;
#pragma unroll
    for (int c = 0; c < NCLS; ++c) se += expf(z[c] - m);
    float lse = m + logf(se);
    float* orow = out + (size_t)node * NCLS;
#pragma unroll
    for (int c = 0; c < NCLS; ++c) orow[c] = z[c] - lse;
}

// ---------------- launch ----------------

extern "C" void kernel_launch(void* const* d_in, const int* in_sizes, int n_in,
                              void* d_out, int out_size, void* d_ws, size_t ws_size,
                              hipStream_t stream) {
    const float* x  = (const float*)d_in[0];
    const int*   ei = (const int*)d_in[1];
    const float* w1 = (const float*)d_in[2];
    const float* b1 = (const float*)d_in[3];
    const float* w2 = (const float*)d_in[4];
    const float* b2 = (const float*)d_in[5];
    float* out = (float*)d_out;

    int N = in_sizes[0] / FIN;     // 100000
    int E = in_sizes[1] / 2;       // 3200000
    int nb = (N + 255) >> SHIFT;   // 391 coarse buckets (<= NBCAP)

    // workspace carve-up (256B-aligned chunks)
    char* p = (char*)d_ws;
    auto alloc = [&](size_t bytes) -> char* {
        char* r = p;
        p += (bytes + 255) / 256 * 256;
        return r;
    };
    int*   hist_src_g = (int*)alloc((size_t)NBLK * NBCAP * 4);   // 1 MB
    int*   hist_tgt_g = (int*)alloc((size_t)NBLK * NBCAP * 4);   // 1 MB
    int*   btot       = (int*)alloc((size_t)2 * NBCAP * 4);
    int*   src_base   = (int*)alloc((size_t)(nb + 1) * 4);
    int*   tgt_base   = (int*)alloc((size_t)(nb + 1) * 4);
    float* dinv       = (float*)alloc((size_t)N * 4);
    int*   row_ptr    = (int*)alloc((size_t)(N + 1) * 4);
    unsigned char* tmp_src = (unsigned char*)alloc((size_t)E);       // 3.2 MB
    unsigned int*  tmp_tgt = (unsigned int*)alloc((size_t)E * 4);    // 12.8 MB
    int*   edges      = (int*)alloc((size_t)E * 4);                  // 12.8 MB
    float* h1         = (float*)alloc((size_t)N * HID * 4);          // 6.4 MB
    float* g          = (float*)alloc((size_t)N * HID * 4);          // 6.4 MB
    float* rowsum     = (float*)alloc((size_t)N * 4);

    int nbN = (N + 255) / 256;     // node-parallel blocks

    count_kernel<<<NBLK, 256, 0, stream>>>(ei, E, nb, hist_src_g, hist_tgt_g);
    colscan_kernel<<<dim3(nb, 2), NBLK, 0, stream>>>(hist_src_g, hist_tgt_g, btot);
    bucketscan_kernel<<<1, 512, 0, stream>>>(btot, nb, src_base, tgt_base, row_ptr, N, E);
    scatter_kernel<<<NBLK, 256, 0, stream>>>(ei, E, nb, hist_src_g, hist_tgt_g,
                                             src_base, tgt_base, tmp_src, tmp_tgt);
    finedeg_kernel<<<nb, 256, 0, stream>>>(tmp_src, src_base, dinv, N);
    finecsr_kernel<<<nb, 256, 0, stream>>>(tmp_tgt, tgt_base, row_ptr, edges, N);
    linear1_kernel<<<nbN, 256, 0, stream>>>(x, w1, b1, h1, N);
    agg_kernel<<<(N * 16 + 255) / 256, 256, 0, stream>>>(h1, edges, row_ptr, dinv, g, rowsum, N, 1);
    agg_kernel<<<(N * 16 + 255) / 256, 256, 0, stream>>>(g, edges, row_ptr, dinv, h1, nullptr, N, 0);
    final_kernel<<<nbN, 256, 0, stream>>>(h1, rowsum, w2, b2, out, N);
}

// Round 3
// 594.531 us; speedup vs baseline: 1.4064x; 1.0024x over previous
//
#include <hip/hip_runtime.h>
#include <hip/hip_fp16.h>
#include <cstdint>

#define FIN 512
#define HID 16
#define NCLS 40
#define SHIFT 8          // 256 nodes per coarse bucket
#define NBCAP 512        // LDS capacity for bucket count (nb = 391 for N=100000)
#define NBLK 512         // blocks for count/scatter (must match between the two)
#define BR 128           // rows per block in linear1
#define KC 32            // K-chunk in linear1

// ---------------- coarse count: per-block LDS histograms over buckets ----------------

__global__ void count_kernel(const int* __restrict__ ei, int E, int nb,
                             int* __restrict__ hist_src_g, int* __restrict__ hist_tgt_g) {
    __shared__ int hs[NBCAP], ht[NBCAP];
    for (int j = threadIdx.x; j < NBCAP; j += 256) { hs[j] = 0; ht[j] = 0; }
    __syncthreads();
    for (int i = blockIdx.x * 256 + threadIdx.x; i < E; i += NBLK * 256) {
        atomicAdd(&hs[ei[i] >> SHIFT], 1);        // src bucket
        atomicAdd(&ht[ei[E + i] >> SHIFT], 1);    // tgt bucket
    }
    __syncthreads();
    int base = blockIdx.x * NBCAP;
    for (int j = threadIdx.x; j < NBCAP; j += 256) {
        hist_src_g[base + j] = hs[j];
        hist_tgt_g[base + j] = ht[j];
    }
}

// ---------------- column scan: per-bucket exclusive scan over blocks ----------------

__global__ void colscan_kernel(int* __restrict__ hist_src_g, int* __restrict__ hist_tgt_g,
                               int* __restrict__ btot) {
    __shared__ int tmp[NBLK];
    int b = blockIdx.x;
    int* h = blockIdx.y ? hist_tgt_g : hist_src_g;
    int t = threadIdx.x;
    int v = h[t * NBCAP + b];
    tmp[t] = v;
    __syncthreads();
    for (int off = 1; off < NBLK; off <<= 1) {
        int a = (t >= off) ? tmp[t - off] : 0;
        __syncthreads();
        tmp[t] += a;
        __syncthreads();
    }
    h[t * NBCAP + b] = tmp[t] - v;
    if (t == NBLK - 1) btot[blockIdx.y * NBCAP + b] = tmp[NBLK - 1];
}

// ---------------- bucket scan: exclusive scan of bucket totals ----------------

__global__ void bucketscan_kernel(const int* __restrict__ btot, int nb,
                                  int* __restrict__ src_base, int* __restrict__ tgt_base,
                                  int* __restrict__ row_ptr, int N, int E) {
    __shared__ int tmp[512];
    int t = threadIdx.x;
    int v = (t < nb) ? btot[t] : 0;
    tmp[t] = v;
    __syncthreads();
    for (int off = 1; off < 512; off <<= 1) {
        int a = (t >= off) ? tmp[t - off] : 0;
        __syncthreads();
        tmp[t] += a;
        __syncthreads();
    }
    if (t < nb) src_base[t] = tmp[t] - v;
    __syncthreads();
    int v2 = (t < nb) ? btot[NBCAP + t] : 0;
    tmp[t] = v2;
    __syncthreads();
    for (int off = 1; off < 512; off <<= 1) {
        int a = (t >= off) ? tmp[t - off] : 0;
        __syncthreads();
        tmp[t] += a;
        __syncthreads();
    }
    if (t < nb) tgt_base[t] = tmp[t] - v2;
    if (t == 0) { src_base[nb] = E; tgt_base[nb] = E; row_ptr[N] = E; }
}

// ---------------- coarse scatter: LDS cursors, no global atomics ----------------

__global__ void scatter_kernel(const int* __restrict__ ei, int E, int nb,
                               const int* __restrict__ hist_src_g,
                               const int* __restrict__ hist_tgt_g,
                               const int* __restrict__ src_base,
                               const int* __restrict__ tgt_base,
                               unsigned char* __restrict__ tmp_src,
                               unsigned int* __restrict__ tmp_tgt) {
    __shared__ int cs[NBCAP], ct[NBCAP];
    int blk = blockIdx.x;
    for (int j = threadIdx.x; j < nb; j += 256) {
        cs[j] = src_base[j] + hist_src_g[blk * NBCAP + j];
        ct[j] = tgt_base[j] + hist_tgt_g[blk * NBCAP + j];
    }
    __syncthreads();
    for (int i = blk * 256 + threadIdx.x; i < E; i += NBLK * 256) {
        int s = ei[i], tg = ei[E + i];
        int ps = atomicAdd(&cs[s >> SHIFT], 1);
        tmp_src[ps] = (unsigned char)(s & 255);
        int pt = atomicAdd(&ct[tg >> SHIFT], 1);
        tmp_tgt[pt] = ((unsigned int)(tg & 255) << 17) | (unsigned int)s;
    }
}

// ---------------- fine: per-bucket deg count -> dinv ----------------

__global__ void finedeg_kernel(const unsigned char* __restrict__ tmp_src,
                               const int* __restrict__ src_base,
                               float* __restrict__ dinv, int N) {
    __shared__ int hist[256];
    int b = blockIdx.x;
    int t = threadIdx.x;
    hist[t] = 0;
    __syncthreads();
    int beg = src_base[b], end = src_base[b + 1];
    for (int i = beg + t; i < end; i += 256)
        atomicAdd(&hist[tmp_src[i]], 1);
    __syncthreads();
    int node = b * 256 + t;
    if (node < N) dinv[node] = rsqrtf((float)(hist[t] + 1));   // +1 self loop
}

// ---------------- fine: per-bucket CSR build (row_ptr + edges=src only) ----------------

__global__ void finecsr_kernel(const unsigned int* __restrict__ tmp_tgt,
                               const int* __restrict__ tgt_base,
                               int* __restrict__ row_ptr, int* __restrict__ edges, int N) {
    __shared__ int hist[256];
    __shared__ int scan[256];
    int b = blockIdx.x;
    int t = threadIdx.x;
    hist[t] = 0;
    __syncthreads();
    int beg = tgt_base[b], end = tgt_base[b + 1];
    for (int i = beg + t; i < end; i += 256)
        atomicAdd(&hist[tmp_tgt[i] >> 17], 1);
    __syncthreads();
    int v = hist[t];
    scan[t] = v;
    __syncthreads();
    for (int off = 1; off < 256; off <<= 1) {
        int a = (t >= off) ? scan[t - off] : 0;
        __syncthreads();
        scan[t] += a;
        __syncthreads();
    }
    int ex = scan[t] - v;       // exclusive offset within bucket
    int node = b * 256 + t;
    if (node < N) row_ptr[node] = beg + ex;
    hist[t] = ex;               // reuse as cursor
    __syncthreads();
    for (int i = beg + t; i < end; i += 256) {
        unsigned int w = tmp_tgt[i];
        int tl = (int)(w >> 17);
        int src = (int)(w & 0x1FFFF);
        int pos = beg + atomicAdd(&hist[tl], 1);
        edges[pos] = src;
    }
}

// ---------------- linear layer 1: h1 = fp16(X @ W1 + b1) ----------------
// 128 rows/block, K-chunks of 32. X staged transposed (xs[k][row]) for
// conflict-free float2 reads; W chunk (2 KB) staged per iteration.
// Thread = 2 rows x 4 channels. LDS ~19 KB -> high occupancy.

__global__ void linear1_kernel(const float* __restrict__ x, const float* __restrict__ w1,
                               const float* __restrict__ b1, __half* __restrict__ h1h, int n) {
    __shared__ float xs[KC][BR + 2];   // [32][130] = 16.6 KB
    __shared__ float wsc[KC][HID];     // 2 KB
    __shared__ float bl[HID];
    int t = threadIdx.x;
    if (t < HID) bl[t] = b1[t];
    int row0 = blockIdx.x * BR;
    int rp = t >> 2;            // 0..63 -> rows 2rp, 2rp+1
    int cq = (t & 3) * 4;       // channel quad
    float acc0[4] = {0, 0, 0, 0};
    float acc1[4] = {0, 0, 0, 0};

    for (int kc = 0; kc < FIN; kc += KC) {
        __syncthreads();   // protect xs/wsc from previous iteration's readers
        // stage W chunk: KC*HID = 512 floats
        for (int i = t; i < KC * HID; i += 256)
            wsc[i >> 4][i & 15] = w1[(kc + (i >> 4)) * HID + (i & 15)];
        // stage X chunk transposed: BR rows x KC cols, float4 global loads
        for (int i = t; i < BR * (KC / 4); i += 256) {
            int rr = i >> 3;            // row in tile (8 float4 per row)
            int c4 = i & 7;
            int grow = row0 + rr;
            float4 v = (grow < n) ? *(const float4*)(x + (size_t)grow * FIN + kc + c4 * 4)
                                  : make_float4(0.f, 0.f, 0.f, 0.f);
            int kk = c4 * 4;
            xs[kk][rr] = v.x; xs[kk + 1][rr] = v.y; xs[kk + 2][rr] = v.z; xs[kk + 3][rr] = v.w;
        }
        __syncthreads();
#pragma unroll 8
        for (int k = 0; k < KC; ++k) {
            float2 xv = *(const float2*)&xs[k][2 * rp];
            float4 wv = *(const float4*)&wsc[k][cq];
            acc0[0] = fmaf(xv.x, wv.x, acc0[0]);
            acc0[1] = fmaf(xv.x, wv.y, acc0[1]);
            acc0[2] = fmaf(xv.x, wv.z, acc0[2]);
            acc0[3] = fmaf(xv.x, wv.w, acc0[3]);
            acc1[0] = fmaf(xv.y, wv.x, acc1[0]);
            acc1[1] = fmaf(xv.y, wv.y, acc1[1]);
            acc1[2] = fmaf(xv.y, wv.z, acc1[2]);
            acc1[3] = fmaf(xv.y, wv.w, acc1[3]);
        }
    }
    int r0 = row0 + 2 * rp;
    if (r0 < n) {
        __half2* hp = (__half2*)(h1h + (size_t)r0 * HID + cq);
        hp[0] = __floats2half2_rn(acc0[0] + bl[cq + 0], acc0[1] + bl[cq + 1]);
        hp[1] = __floats2half2_rn(acc0[2] + bl[cq + 2], acc0[3] + bl[cq + 3]);
    }
    if (r0 + 1 < n) {
        __half2* hp = (__half2*)(h1h + (size_t)(r0 + 1) * HID + cq);
        hp[0] = __floats2half2_rn(acc1[0] + bl[cq + 0], acc1[1] + bl[cq + 1]);
        hp[1] = __floats2half2_rn(acc1[2] + bl[cq + 2], acc1[3] + bl[cq + 3]);
    }
}

// ---------------- pull aggregation (8 lanes per node, lane = channel pair) ----------------
// out[t][c] = dinv[t]^2 * in[t][c] + sum_{e: tgt==t} dinv[src]*dinv[t] * in[src][c]
// in: fp16 table (32 B/node). out: fp16 table (agg1) or fp32 (agg2).

__global__ void agg_kernel(const __half* __restrict__ in, const int* __restrict__ edges,
                           const int* __restrict__ row_ptr, const float* __restrict__ dinv,
                           __half* __restrict__ out16, float* __restrict__ out32,
                           float* __restrict__ rowsum, int n, int do_relu) {
    int gid = blockIdx.x * blockDim.x + threadIdx.x;
    int node = gid >> 3;
    int c2 = gid & 7;          // channel pair
    if (node >= n) return;
    const __half2* tab = (const __half2*)in;   // 8 __half2 per node
    float dv = dinv[node];
    float self = dv * dv;
    float2 sv = __half22float2(tab[node * 8 + c2]);
    float a0 = self * sv.x, a1 = self * sv.y;
    float rs = self;
    int beg = row_ptr[node], end = row_ptr[node + 1];
    for (int i = beg; i < end; ++i) {
        int src = edges[i];
        float nrm = dinv[src] * dv;
        float2 v = __half22float2(tab[src * 8 + c2]);
        a0 = fmaf(nrm, v.x, a0);
        a1 = fmaf(nrm, v.y, a1);
        rs += nrm;
    }
    if (do_relu) { a0 = fmaxf(a0, 0.0f); a1 = fmaxf(a1, 0.0f); }
    if (out16 != nullptr) {
        ((__half2*)out16)[node * 8 + c2] = __floats2half2_rn(a0, a1);
    } else {
        ((float2*)out32)[node * 8 + c2] = make_float2(a0, a1);
    }
    if (rowsum != nullptr && c2 == 0) rowsum[node] = rs;
}

// ---------------- final: out = (q @ W2) + rowsum*b2, then log_softmax ----------------

__global__ void final_kernel(const float* __restrict__ q, const float* __restrict__ rowsum,
                             const float* __restrict__ w2, const float* __restrict__ b2,
                             float* __restrict__ out, int n) {
    __shared__ float wl[HID * NCLS];
    __shared__ float bl[NCLS];
    for (int i = threadIdx.x; i < HID * NCLS; i += blockDim.x) wl[i] = w2[i];
    if (threadIdx.x < NCLS) bl[threadIdx.x] = b2[threadIdx.x];
    __syncthreads();
    int node = blockIdx.x * blockDim.x + threadIdx.x;
    if (node >= n) return;
    float h[HID];
#pragma unroll
    for (int j = 0; j < HID; ++j) h[j] = q[(size_t)node * HID + j];
    float rs = rowsum[node];
    float z[NCLS];
#pragma unroll
    for (int c = 0; c < NCLS; ++c) {
        float s = rs * bl[c];
#pragma unroll
        for (int j = 0; j < HID; ++j) s = fmaf(h[j], wl[j * NCLS + c], s);
        z[c] = s;
    }
    float m = z[0];
#pragma unroll
    for (int c = 1; c < NCLS; ++c) m = fmaxf(m, z[c]);
    float se = 0.0f;
#pragma unroll
    for (int c = 0; c < NCLS; ++c) se += expf(z[c] - m);
    float lse = m + logf(se);
    float* orow = out + (size_t)node * NCLS;
#pragma unroll
    for (int c = 0; c < NCLS; ++c) orow[c] = z[c] - lse;
}

// ---------------- launch ----------------

extern "C" void kernel_launch(void* const* d_in, const int* in_sizes, int n_in,
                              void* d_out, int out_size, void* d_ws, size_t ws_size,
                              hipStream_t stream) {
    const float* x  = (const float*)d_in[0];
    const int*   ei = (const int*)d_in[1];
    const float* w1 = (const float*)d_in[2];
    const float* b1 = (const float*)d_in[3];
    const float* w2 = (const float*)d_in[4];
    const float* b2 = (const float*)d_in[5];
    float* out = (float*)d_out;

    int N = in_sizes[0] / FIN;     // 100000
    int E = in_sizes[1] / 2;       // 3200000
    int nb = (N + 255) >> SHIFT;   // 391 coarse buckets (<= NBCAP)

    // workspace carve-up (256B-aligned chunks)
    char* p = (char*)d_ws;
    auto alloc = [&](size_t bytes) -> char* {
        char* r = p;
        p += (bytes + 255) / 256 * 256;
        return r;
    };
    int*   hist_src_g = (int*)alloc((size_t)NBLK * NBCAP * 4);   // 1 MB
    int*   hist_tgt_g = (int*)alloc((size_t)NBLK * NBCAP * 4);   // 1 MB
    int*   btot       = (int*)alloc((size_t)2 * NBCAP * 4);
    int*   src_base   = (int*)alloc((size_t)(nb + 1) * 4);
    int*   tgt_base   = (int*)alloc((size_t)(nb + 1) * 4);
    float* dinv       = (float*)alloc((size_t)N * 4);
    int*   row_ptr    = (int*)alloc((size_t)(N + 1) * 4);
    unsigned char* tmp_src = (unsigned char*)alloc((size_t)E);       // 3.2 MB
    unsigned int*  tmp_tgt = (unsigned int*)alloc((size_t)E * 4);    // 12.8 MB
    int*   edges      = (int*)alloc((size_t)E * 4);                  // 12.8 MB
    __half* h1h       = (__half*)alloc((size_t)N * HID * 2);         // 3.2 MB
    __half* gh        = (__half*)alloc((size_t)N * HID * 2);         // 3.2 MB
    float* h2         = (float*)alloc((size_t)N * HID * 4);          // 6.4 MB
    float* rowsum     = (float*)alloc((size_t)N * 4);

    int nbN = (N + 255) / 256;     // node-parallel blocks

    count_kernel<<<NBLK, 256, 0, stream>>>(ei, E, nb, hist_src_g, hist_tgt_g);
    colscan_kernel<<<dim3(nb, 2), NBLK, 0, stream>>>(hist_src_g, hist_tgt_g, btot);
    bucketscan_kernel<<<1, 512, 0, stream>>>(btot, nb, src_base, tgt_base, row_ptr, N, E);
    scatter_kernel<<<NBLK, 256, 0, stream>>>(ei, E, nb, hist_src_g, hist_tgt_g,
                                             src_base, tgt_base, tmp_src, tmp_tgt);
    finedeg_kernel<<<nb, 256, 0, stream>>>(tmp_src, src_base, dinv, N);
    finecsr_kernel<<<nb, 256, 0, stream>>>(tmp_tgt, tgt_base, row_ptr, edges, N);
    linear1_kernel<<<(N + BR - 1) / BR, 256, 0, stream>>>(x, w1, b1, h1h, N);
    agg_kernel<<<(N * 8 + 255) / 256, 256, 0, stream>>>(h1h, edges, row_ptr, dinv,
                                                        gh, nullptr, rowsum, N, 1);
    agg_kernel<<<(N * 8 + 255) / 256, 256, 0, stream>>>(gh, edges, row_ptr, dinv,
                                                        nullptr, h2, nullptr, N, 0);
    final_kernel<<<nbN, 256, 0, stream>>>(h2, rowsum, w2, b2, out, N);
}

// Round 4
// 546.636 us; speedup vs baseline: 1.5297x; 1.0876x over previous
//
#include <hip/hip_runtime.h>
#include <hip/hip_fp16.h>
#include <cstdint>

#define FIN 512
#define HID 16
#define NCLS 40
#define SHIFT 8          // 256 nodes per coarse bucket
#define NBCAP 512        // LDS capacity for bucket count (nb = 391 for N=100000)
#define NBLK 512         // blocks for count/scatter (must match between the two)
#define BR 128           // rows per block in linear1
#define KC 32            // K-chunk in linear1

// ---------------- coarse count: per-block LDS histograms over buckets ----------------

__global__ void count_kernel(const int* __restrict__ ei, int E, int nb,
                             int* __restrict__ hist_src_g, int* __restrict__ hist_tgt_g) {
    __shared__ int hs[NBCAP], ht[NBCAP];
    for (int j = threadIdx.x; j < NBCAP; j += 256) { hs[j] = 0; ht[j] = 0; }
    __syncthreads();
    for (int i = blockIdx.x * 256 + threadIdx.x; i < E; i += NBLK * 256) {
        atomicAdd(&hs[ei[i] >> SHIFT], 1);        // src bucket
        atomicAdd(&ht[ei[E + i] >> SHIFT], 1);    // tgt bucket
    }
    __syncthreads();
    int base = blockIdx.x * NBCAP;
    for (int j = threadIdx.x; j < NBCAP; j += 256) {
        hist_src_g[base + j] = hs[j];
        hist_tgt_g[base + j] = ht[j];
    }
}

// ---------------- column scan: per-bucket exclusive scan over blocks ----------------

__global__ void colscan_kernel(int* __restrict__ hist_src_g, int* __restrict__ hist_tgt_g,
                               int* __restrict__ btot) {
    __shared__ int tmp[NBLK];
    int b = blockIdx.x;
    int* h = blockIdx.y ? hist_tgt_g : hist_src_g;
    int t = threadIdx.x;
    int v = h[t * NBCAP + b];
    tmp[t] = v;
    __syncthreads();
    for (int off = 1; off < NBLK; off <<= 1) {
        int a = (t >= off) ? tmp[t - off] : 0;
        __syncthreads();
        tmp[t] += a;
        __syncthreads();
    }
    h[t * NBCAP + b] = tmp[t] - v;
    if (t == NBLK - 1) btot[blockIdx.y * NBCAP + b] = tmp[NBLK - 1];
}

// ---------------- bucket scan: exclusive scan of bucket totals ----------------

__global__ void bucketscan_kernel(const int* __restrict__ btot, int nb,
                                  int* __restrict__ src_base, int* __restrict__ tgt_base,
                                  int* __restrict__ row_ptr, int N, int E) {
    __shared__ int tmp[512];
    int t = threadIdx.x;
    int v = (t < nb) ? btot[t] : 0;
    tmp[t] = v;
    __syncthreads();
    for (int off = 1; off < 512; off <<= 1) {
        int a = (t >= off) ? tmp[t - off] : 0;
        __syncthreads();
        tmp[t] += a;
        __syncthreads();
    }
    if (t < nb) src_base[t] = tmp[t] - v;
    __syncthreads();
    int v2 = (t < nb) ? btot[NBCAP + t] : 0;
    tmp[t] = v2;
    __syncthreads();
    for (int off = 1; off < 512; off <<= 1) {
        int a = (t >= off) ? tmp[t - off] : 0;
        __syncthreads();
        tmp[t] += a;
        __syncthreads();
    }
    if (t < nb) tgt_base[t] = tmp[t] - v2;
    if (t == 0) { src_base[nb] = E; tgt_base[nb] = E; row_ptr[N] = E; }
}

// ---------------- coarse scatter: LDS cursors, no global atomics ----------------

__global__ void scatter_kernel(const int* __restrict__ ei, int E, int nb,
                               const int* __restrict__ hist_src_g,
                               const int* __restrict__ hist_tgt_g,
                               const int* __restrict__ src_base,
                               const int* __restrict__ tgt_base,
                               unsigned char* __restrict__ tmp_src,
                               unsigned int* __restrict__ tmp_tgt) {
    __shared__ int cs[NBCAP], ct[NBCAP];
    int blk = blockIdx.x;
    for (int j = threadIdx.x; j < nb; j += 256) {
        cs[j] = src_base[j] + hist_src_g[blk * NBCAP + j];
        ct[j] = tgt_base[j] + hist_tgt_g[blk * NBCAP + j];
    }
    __syncthreads();
    for (int i = blk * 256 + threadIdx.x; i < E; i += NBLK * 256) {
        int s = ei[i], tg = ei[E + i];
        int ps = atomicAdd(&cs[s >> SHIFT], 1);
        tmp_src[ps] = (unsigned char)(s & 255);
        int pt = atomicAdd(&ct[tg >> SHIFT], 1);
        tmp_tgt[pt] = ((unsigned int)(tg & 255) << 17) | (unsigned int)s;
    }
}

// ---------------- fine: per-bucket deg count -> dinv ----------------

__global__ void finedeg_kernel(const unsigned char* __restrict__ tmp_src,
                               const int* __restrict__ src_base,
                               float* __restrict__ dinv, int N) {
    __shared__ int hist[256];
    int b = blockIdx.x;
    int t = threadIdx.x;
    hist[t] = 0;
    __syncthreads();
    int beg = src_base[b], end = src_base[b + 1];
    for (int i = beg + t; i < end; i += 256)
        atomicAdd(&hist[tmp_src[i]], 1);
    __syncthreads();
    int node = b * 256 + t;
    if (node < N) dinv[node] = rsqrtf((float)(hist[t] + 1));   // +1 self loop
}

// ---------------- fine: per-bucket CSR build (row_ptr + edges + edinv) ----------------

__global__ void finecsr_kernel(const unsigned int* __restrict__ tmp_tgt,
                               const int* __restrict__ tgt_base,
                               const float* __restrict__ dinv,
                               int* __restrict__ row_ptr, int* __restrict__ edges,
                               __half* __restrict__ edinv, int N) {
    __shared__ int hist[256];
    __shared__ int scan[256];
    int b = blockIdx.x;
    int t = threadIdx.x;
    hist[t] = 0;
    __syncthreads();
    int beg = tgt_base[b], end = tgt_base[b + 1];
    for (int i = beg + t; i < end; i += 256)
        atomicAdd(&hist[tmp_tgt[i] >> 17], 1);
    __syncthreads();
    int v = hist[t];
    scan[t] = v;
    __syncthreads();
    for (int off = 1; off < 256; off <<= 1) {
        int a = (t >= off) ? scan[t - off] : 0;
        __syncthreads();
        scan[t] += a;
        __syncthreads();
    }
    int ex = scan[t] - v;       // exclusive offset within bucket
    int node = b * 256 + t;
    if (node < N) row_ptr[node] = beg + ex;
    hist[t] = ex;               // reuse as cursor
    __syncthreads();
    for (int i = beg + t; i < end; i += 256) {
        unsigned int w = tmp_tgt[i];
        int tl = (int)(w >> 17);
        int src = (int)(w & 0x1FFFF);
        int pos = beg + atomicAdd(&hist[tl], 1);
        edges[pos] = src;
        edinv[pos] = __float2half(dinv[src]);
    }
}

// ---------------- linear layer 1: h1 = fp16(X @ W1 + b1) ----------------
// Software-pipelined: next K-chunk prefetched into registers while current
// chunk computes from LDS. X staged transposed for conflict-free reads.

__global__ void linear1_kernel(const float* __restrict__ x, const float* __restrict__ w1,
                               const float* __restrict__ b1, __half* __restrict__ h1h, int n) {
    __shared__ float xs[KC][BR + 2];   // [32][130] = 16.6 KB
    __shared__ float wsc[KC * HID];    // 2 KB
    __shared__ float bl[HID];
    int t = threadIdx.x;
    if (t < HID) bl[t] = b1[t];
    int row0 = blockIdx.x * BR;
    int rp = t >> 2;            // 0..63 -> rows 2rp, 2rp+1
    int cq = (t & 3) * 4;       // channel quad
    float acc0[4] = {0, 0, 0, 0};
    float acc1[4] = {0, 0, 0, 0};

    // prefetch registers: 4 float4 of X + 2 floats of W per thread
    float4 xp[4];
    float wp[2];
    int rr_[4], kk_[4];
#pragma unroll
    for (int u = 0; u < 4; ++u) {
        int i = t + u * 256;
        rr_[u] = i >> 3;            // row in tile
        kk_[u] = (i & 7) * 4;       // k within chunk
    }
    auto prefetch = [&](int kc) {
#pragma unroll
        for (int u = 0; u < 4; ++u) {
            int grow = row0 + rr_[u];
            xp[u] = (grow < n) ? *(const float4*)(x + (size_t)grow * FIN + kc + kk_[u])
                               : make_float4(0.f, 0.f, 0.f, 0.f);
        }
        wp[0] = w1[kc * HID + t];
        wp[1] = w1[kc * HID + t + 256];
    };

    prefetch(0);
    for (int kc = 0; kc < FIN; kc += KC) {
        __syncthreads();   // previous compute done before overwriting LDS
#pragma unroll
        for (int u = 0; u < 4; ++u) {
            xs[kk_[u] + 0][rr_[u]] = xp[u].x;
            xs[kk_[u] + 1][rr_[u]] = xp[u].y;
            xs[kk_[u] + 2][rr_[u]] = xp[u].z;
            xs[kk_[u] + 3][rr_[u]] = xp[u].w;
        }
        wsc[t] = wp[0];
        wsc[t + 256] = wp[1];
        __syncthreads();
        if (kc + KC < FIN) prefetch(kc + KC);   // overlap with compute below
#pragma unroll 8
        for (int k = 0; k < KC; ++k) {
            float2 xv = *(const float2*)&xs[k][2 * rp];
            float4 wv = *(const float4*)&wsc[k * HID + cq];
            acc0[0] = fmaf(xv.x, wv.x, acc0[0]);
            acc0[1] = fmaf(xv.x, wv.y, acc0[1]);
            acc0[2] = fmaf(xv.x, wv.z, acc0[2]);
            acc0[3] = fmaf(xv.x, wv.w, acc0[3]);
            acc1[0] = fmaf(xv.y, wv.x, acc1[0]);
            acc1[1] = fmaf(xv.y, wv.y, acc1[1]);
            acc1[2] = fmaf(xv.y, wv.z, acc1[2]);
            acc1[3] = fmaf(xv.y, wv.w, acc1[3]);
        }
    }
    int r0 = row0 + 2 * rp;
    if (r0 < n) {
        __half2* hp = (__half2*)(h1h + (size_t)r0 * HID + cq);
        hp[0] = __floats2half2_rn(acc0[0] + bl[cq + 0], acc0[1] + bl[cq + 1]);
        hp[1] = __floats2half2_rn(acc0[2] + bl[cq + 2], acc0[3] + bl[cq + 3]);
    }
    if (r0 + 1 < n) {
        __half2* hp = (__half2*)(h1h + (size_t)(r0 + 1) * HID + cq);
        hp[0] = __floats2half2_rn(acc1[0] + bl[cq + 0], acc1[1] + bl[cq + 1]);
        hp[1] = __floats2half2_rn(acc1[2] + bl[cq + 2], acc1[3] + bl[cq + 3]);
    }
}

// ---------------- agg1: 16 threads/node (2 edge-halves x 8 channel-pairs) ----------------
// out[t][c] = relu( dinv[t]^2*in[t][c] + sum_e dinv[src]*dinv[t]*in[src][c] )

__global__ void agg1_kernel(const __half* __restrict__ in, const int* __restrict__ edges,
                            const __half* __restrict__ edinv, const int* __restrict__ row_ptr,
                            const float* __restrict__ dinv, __half* __restrict__ out16,
                            float* __restrict__ rowsum, int n) {
    int gid = blockIdx.x * blockDim.x + threadIdx.x;
    int node = gid >> 4;
    int sub = (gid >> 3) & 1;
    int c2 = gid & 7;
    if (node >= n) return;
    const __half2* tab = (const __half2*)in;
    float dv = dinv[node];
    float self = dv * dv;
    float a0 = 0.f, a1 = 0.f, rs = 0.f;
    if (sub == 0) {
        float2 sv = __half22float2(tab[(size_t)node * 8 + c2]);
        a0 = self * sv.x; a1 = self * sv.y; rs = self;
    }
    int beg = row_ptr[node], end = row_ptr[node + 1];
#pragma unroll 4
    for (int i = beg + sub; i < end; i += 2) {
        int src = edges[i];
        float nrm = __half2float(edinv[i]) * dv;
        float2 v = __half22float2(tab[(size_t)src * 8 + c2]);
        a0 = fmaf(nrm, v.x, a0);
        a1 = fmaf(nrm, v.y, a1);
        rs += nrm;
    }
    a0 += __shfl_xor(a0, 8);
    a1 += __shfl_xor(a1, 8);
    rs += __shfl_xor(rs, 8);
    if (sub == 0) {
        a0 = fmaxf(a0, 0.f); a1 = fmaxf(a1, 0.f);
        ((__half2*)out16)[(size_t)node * 8 + c2] = __floats2half2_rn(a0, a1);
        if (c2 == 0) rowsum[node] = rs;
    }
}

// ---------------- agg2 + final fused: out = log_softmax((A g) W2 + rowsum*b2) ----------
// 256 threads = 16 nodes x 16 threads; aggregated features staged through LDS,
// epilogue (40-ch linear + log_softmax) on 2 threads/node.

__global__ void agg2_kernel(const __half* __restrict__ in, const int* __restrict__ edges,
                            const __half* __restrict__ edinv, const int* __restrict__ row_ptr,
                            const float* __restrict__ dinv, const float* __restrict__ rowsum,
                            const float* __restrict__ w2, const float* __restrict__ b2,
                            float* __restrict__ out, int n) {
    __shared__ float g2[16][HID + 1];
    __shared__ float wl[HID * NCLS];
    __shared__ float bl[NCLS];
    int t = threadIdx.x;
    for (int i = t; i < HID * NCLS; i += 256) wl[i] = w2[i];
    if (t < NCLS) bl[t] = b2[t];
    int gid = blockIdx.x * 256 + t;
    int node = gid >> 4;
    int sub = (t >> 3) & 1;
    int c2 = t & 7;
    int nl = t >> 4;
    float a0 = 0.f, a1 = 0.f;
    if (node < n) {
        const __half2* tab = (const __half2*)in;
        float dv = dinv[node];
        float self = dv * dv;
        if (sub == 0) {
            float2 sv = __half22float2(tab[(size_t)node * 8 + c2]);
            a0 = self * sv.x; a1 = self * sv.y;
        }
        int beg = row_ptr[node], end = row_ptr[node + 1];
#pragma unroll 4
        for (int i = beg + sub; i < end; i += 2) {
            int src = edges[i];
            float nrm = __half2float(edinv[i]) * dv;
            float2 v = __half22float2(tab[(size_t)src * 8 + c2]);
            a0 = fmaf(nrm, v.x, a0);
            a1 = fmaf(nrm, v.y, a1);
        }
    }
    a0 += __shfl_xor(a0, 8);
    a1 += __shfl_xor(a1, 8);
    if (sub == 0) { g2[nl][c2 * 2] = a0; g2[nl][c2 * 2 + 1] = a1; }
    __syncthreads();
    if (t < 32) {
        int nl2 = t >> 1, half = t & 1;
        int node2 = blockIdx.x * 16 + nl2;
        float z[20];
        float m = -1e30f, se = 0.f, lse = 0.f;
        if (node2 < n) {
            float h[HID];
#pragma unroll
            for (int j = 0; j < HID; ++j) h[j] = g2[nl2][j];
            float rs = rowsum[node2];
            int c0 = half * 20;
#pragma unroll
            for (int c = 0; c < 20; ++c) {
                float s = rs * bl[c0 + c];
#pragma unroll
                for (int j = 0; j < HID; ++j) s = fmaf(h[j], wl[j * NCLS + c0 + c], s);
                z[c] = s;
            }
            m = z[0];
#pragma unroll
            for (int c = 1; c < 20; ++c) m = fmaxf(m, z[c]);
        }
        m = fmaxf(m, __shfl_xor(m, 1));
        if (node2 < n) {
#pragma unroll
            for (int c = 0; c < 20; ++c) se += __expf(z[c] - m);
        }
        se += __shfl_xor(se, 1);
        if (node2 < n) {
            lse = m + __logf(se);
            float* orow = out + (size_t)node2 * NCLS + half * 20;
#pragma unroll
            for (int c = 0; c < 20; ++c) orow[c] = z[c] - lse;
        }
    }
}

// ---------------- launch ----------------

extern "C" void kernel_launch(void* const* d_in, const int* in_sizes, int n_in,
                              void* d_out, int out_size, void* d_ws, size_t ws_size,
                              hipStream_t stream) {
    const float* x  = (const float*)d_in[0];
    const int*   ei = (const int*)d_in[1];
    const float* w1 = (const float*)d_in[2];
    const float* b1 = (const float*)d_in[3];
    const float* w2 = (const float*)d_in[4];
    const float* b2 = (const float*)d_in[5];
    float* out = (float*)d_out;

    int N = in_sizes[0] / FIN;     // 100000
    int E = in_sizes[1] / 2;       // 3200000
    int nb = (N + 255) >> SHIFT;   // 391 coarse buckets (<= NBCAP)

    char* p = (char*)d_ws;
    auto alloc = [&](size_t bytes) -> char* {
        char* r = p;
        p += (bytes + 255) / 256 * 256;
        return r;
    };
    int*   hist_src_g = (int*)alloc((size_t)NBLK * NBCAP * 4);   // 1 MB
    int*   hist_tgt_g = (int*)alloc((size_t)NBLK * NBCAP * 4);   // 1 MB
    int*   btot       = (int*)alloc((size_t)2 * NBCAP * 4);
    int*   src_base   = (int*)alloc((size_t)(nb + 1) * 4);
    int*   tgt_base   = (int*)alloc((size_t)(nb + 1) * 4);
    float* dinv       = (float*)alloc((size_t)N * 4);
    int*   row_ptr    = (int*)alloc((size_t)(N + 1) * 4);
    unsigned char* tmp_src = (unsigned char*)alloc((size_t)E);       // 3.2 MB
    unsigned int*  tmp_tgt = (unsigned int*)alloc((size_t)E * 4);    // 12.8 MB
    int*    edges     = (int*)alloc((size_t)E * 4);                  // 12.8 MB
    __half* edinv     = (__half*)alloc((size_t)E * 2);               // 6.4 MB
    __half* h1h       = (__half*)alloc((size_t)N * HID * 2);         // 3.2 MB
    __half* gh        = (__half*)alloc((size_t)N * HID * 2);         // 3.2 MB
    float*  rowsum    = (float*)alloc((size_t)N * 4);

    count_kernel<<<NBLK, 256, 0, stream>>>(ei, E, nb, hist_src_g, hist_tgt_g);
    colscan_kernel<<<dim3(nb, 2), NBLK, 0, stream>>>(hist_src_g, hist_tgt_g, btot);
    bucketscan_kernel<<<1, 512, 0, stream>>>(btot, nb, src_base, tgt_base, row_ptr, N, E);
    scatter_kernel<<<NBLK, 256, 0, stream>>>(ei, E, nb, hist_src_g, hist_tgt_g,
                                             src_base, tgt_base, tmp_src, tmp_tgt);
    finedeg_kernel<<<nb, 256, 0, stream>>>(tmp_src, src_base, dinv, N);
    finecsr_kernel<<<nb, 256, 0, stream>>>(tmp_tgt, tgt_base, dinv, row_ptr, edges, edinv, N);
    linear1_kernel<<<(N + BR - 1) / BR, 256, 0, stream>>>(x, w1, b1, h1h, N);
    agg1_kernel<<<(N * 16 + 255) / 256, 256, 0, stream>>>(h1h, edges, edinv, row_ptr, dinv,
                                                          gh, rowsum, N);
    agg2_kernel<<<(N * 16 + 255) / 256, 256, 0, stream>>>(gh, edges, edinv, row_ptr, dinv,
                                                          rowsum, w2, b2, out, N);
}

// Round 6
// 514.022 us; speedup vs baseline: 1.6267x; 1.0634x over previous
//
#include <hip/hip_runtime.h>
#include <hip/hip_fp16.h>
#include <cstdint>

#define FIN 512
#define HID 16
#define NCLS 40
#define SHIFT 8          // 256 nodes per coarse bucket
#define NBCAP 512        // LDS capacity for bucket histograms (nb = 391 for N=100000)
#define NBLK 512         // blocks for count/scatter (must match between the two)
#define BR 64            // rows per block in linear1
#define KC 32            // K-chunk in linear1

// Clang vector types for __builtin_nontemporal_load (HIP_vector_type is a class -> rejected)
typedef int   iv4 __attribute__((ext_vector_type(4)));
typedef float fv4 __attribute__((ext_vector_type(4)));

// ---------------- coarse count: per-block LDS histograms over buckets ----------------

__global__ void count_kernel(const int* __restrict__ ei, int E, int nb,
                             int* __restrict__ hist_src_g, int* __restrict__ hist_tgt_g) {
    __shared__ int hs[NBCAP], ht[NBCAP];
    for (int j = threadIdx.x; j < NBCAP; j += 256) { hs[j] = 0; ht[j] = 0; }
    __syncthreads();
    if ((E & 3) == 0) {
        const iv4* s4 = (const iv4*)ei;
        const iv4* t4 = (const iv4*)(ei + E);
        int E4 = E >> 2;
        for (int i = blockIdx.x * 256 + threadIdx.x; i < E4; i += NBLK * 256) {
            iv4 s = __builtin_nontemporal_load(&s4[i]);
            iv4 t = __builtin_nontemporal_load(&t4[i]);
            atomicAdd(&hs[s.x >> SHIFT], 1); atomicAdd(&hs[s.y >> SHIFT], 1);
            atomicAdd(&hs[s.z >> SHIFT], 1); atomicAdd(&hs[s.w >> SHIFT], 1);
            atomicAdd(&ht[t.x >> SHIFT], 1); atomicAdd(&ht[t.y >> SHIFT], 1);
            atomicAdd(&ht[t.z >> SHIFT], 1); atomicAdd(&ht[t.w >> SHIFT], 1);
        }
    } else {
        for (int i = blockIdx.x * 256 + threadIdx.x; i < E; i += NBLK * 256) {
            atomicAdd(&hs[ei[i] >> SHIFT], 1);
            atomicAdd(&ht[ei[E + i] >> SHIFT], 1);
        }
    }
    __syncthreads();
    int base = blockIdx.x * NBCAP;
    for (int j = threadIdx.x; j < NBCAP; j += 256) {
        hist_src_g[base + j] = hs[j];
        hist_tgt_g[base + j] = ht[j];
    }
}

// ---------------- column scan: per-bucket exclusive scan over blocks ----------------

__global__ void colscan_kernel(int* __restrict__ hist_src_g, int* __restrict__ hist_tgt_g,
                               int* __restrict__ btot) {
    __shared__ int tmp[NBLK];
    int b = blockIdx.x;
    int* h = blockIdx.y ? hist_tgt_g : hist_src_g;
    int t = threadIdx.x;
    int v = h[t * NBCAP + b];
    tmp[t] = v;
    __syncthreads();
    for (int off = 1; off < NBLK; off <<= 1) {
        int a = (t >= off) ? tmp[t - off] : 0;
        __syncthreads();
        tmp[t] += a;
        __syncthreads();
    }
    h[t * NBCAP + b] = tmp[t] - v;
    if (t == NBLK - 1) btot[blockIdx.y * NBCAP + b] = tmp[NBLK - 1];
}

// ---------------- bucket scan: exclusive scan of bucket totals ----------------

__global__ void bucketscan_kernel(const int* __restrict__ btot, int nb,
                                  int* __restrict__ src_base, int* __restrict__ tgt_base,
                                  int* __restrict__ row_ptr, int N, int E) {
    __shared__ int tmp[512];
    int t = threadIdx.x;
    int v = (t < nb) ? btot[t] : 0;
    tmp[t] = v;
    __syncthreads();
    for (int off = 1; off < 512; off <<= 1) {
        int a = (t >= off) ? tmp[t - off] : 0;
        __syncthreads();
        tmp[t] += a;
        __syncthreads();
    }
    if (t < nb) src_base[t] = tmp[t] - v;
    __syncthreads();
    int v2 = (t < nb) ? btot[NBCAP + t] : 0;
    tmp[t] = v2;
    __syncthreads();
    for (int off = 1; off < 512; off <<= 1) {
        int a = (t >= off) ? tmp[t - off] : 0;
        __syncthreads();
        tmp[t] += a;
        __syncthreads();
    }
    if (t < nb) tgt_base[t] = tmp[t] - v2;
    if (t == 0) { src_base[nb] = E; tgt_base[nb] = E; row_ptr[N] = E; }
}

// ---------------- coarse scatter: LDS cursors, no global atomics ----------------
// tmp_src[pos] = low 8 bits of src (bucket implied by position)
// tmp_tgt[pos] = (tgt&255)<<17 | src   (src < 2^17)

__global__ void scatter_kernel(const int* __restrict__ ei, int E, int nb,
                               const int* __restrict__ hist_src_g,
                               const int* __restrict__ hist_tgt_g,
                               const int* __restrict__ src_base,
                               const int* __restrict__ tgt_base,
                               unsigned char* __restrict__ tmp_src,
                               unsigned int* __restrict__ tmp_tgt) {
    __shared__ int cs[NBCAP], ct[NBCAP];
    int blk = blockIdx.x;
    for (int j = threadIdx.x; j < nb; j += 256) {
        cs[j] = src_base[j] + hist_src_g[blk * NBCAP + j];
        ct[j] = tgt_base[j] + hist_tgt_g[blk * NBCAP + j];
    }
    __syncthreads();
    if ((E & 3) == 0) {
        const iv4* s4 = (const iv4*)ei;
        const iv4* t4 = (const iv4*)(ei + E);
        int E4 = E >> 2;
        for (int i = blk * 256 + threadIdx.x; i < E4; i += NBLK * 256) {
            iv4 s = __builtin_nontemporal_load(&s4[i]);
            iv4 t = __builtin_nontemporal_load(&t4[i]);
            int p;
            p = atomicAdd(&cs[s.x >> SHIFT], 1); tmp_src[p] = (unsigned char)(s.x & 255);
            p = atomicAdd(&cs[s.y >> SHIFT], 1); tmp_src[p] = (unsigned char)(s.y & 255);
            p = atomicAdd(&cs[s.z >> SHIFT], 1); tmp_src[p] = (unsigned char)(s.z & 255);
            p = atomicAdd(&cs[s.w >> SHIFT], 1); tmp_src[p] = (unsigned char)(s.w & 255);
            p = atomicAdd(&ct[t.x >> SHIFT], 1); tmp_tgt[p] = ((unsigned int)(t.x & 255) << 17) | (unsigned int)s.x;
            p = atomicAdd(&ct[t.y >> SHIFT], 1); tmp_tgt[p] = ((unsigned int)(t.y & 255) << 17) | (unsigned int)s.y;
            p = atomicAdd(&ct[t.z >> SHIFT], 1); tmp_tgt[p] = ((unsigned int)(t.z & 255) << 17) | (unsigned int)s.z;
            p = atomicAdd(&ct[t.w >> SHIFT], 1); tmp_tgt[p] = ((unsigned int)(t.w & 255) << 17) | (unsigned int)s.w;
        }
    } else {
        for (int i = blk * 256 + threadIdx.x; i < E; i += NBLK * 256) {
            int s = ei[i], tg = ei[E + i];
            int ps = atomicAdd(&cs[s >> SHIFT], 1);
            tmp_src[ps] = (unsigned char)(s & 255);
            int pt = atomicAdd(&ct[tg >> SHIFT], 1);
            tmp_tgt[pt] = ((unsigned int)(tg & 255) << 17) | (unsigned int)s;
        }
    }
}

// ---------------- fine (merged): per-bucket deg->dinv AND CSR build ----------------

__global__ void fine_kernel(const unsigned char* __restrict__ tmp_src,
                            const int* __restrict__ src_base,
                            const unsigned int* __restrict__ tmp_tgt,
                            const int* __restrict__ tgt_base,
                            float* __restrict__ dinv, int* __restrict__ row_ptr,
                            int* __restrict__ edges, int N) {
    __shared__ int hist[256];
    __shared__ int scan[256];
    int b = blockIdx.x;
    int t = threadIdx.x;
    // phase 1: src degree histogram -> dinv
    hist[t] = 0;
    __syncthreads();
    {
        int beg = src_base[b], end = src_base[b + 1];
        for (int i = beg + t; i < end; i += 256)
            atomicAdd(&hist[tmp_src[i]], 1);
    }
    __syncthreads();
    int node = b * 256 + t;
    if (node < N) dinv[node] = rsqrtf((float)(hist[t] + 1));   // +1 self loop
    __syncthreads();
    // phase 2: tgt histogram -> row_ptr -> edge scatter
    hist[t] = 0;
    __syncthreads();
    int beg = tgt_base[b], end = tgt_base[b + 1];
    for (int i = beg + t; i < end; i += 256)
        atomicAdd(&hist[tmp_tgt[i] >> 17], 1);
    __syncthreads();
    int v = hist[t];
    scan[t] = v;
    __syncthreads();
    for (int off = 1; off < 256; off <<= 1) {
        int a = (t >= off) ? scan[t - off] : 0;
        __syncthreads();
        scan[t] += a;
        __syncthreads();
    }
    int ex = scan[t] - v;       // exclusive offset within bucket
    if (node < N) row_ptr[node] = beg + ex;
    hist[t] = ex;               // reuse as cursor
    __syncthreads();
    for (int i = beg + t; i < end; i += 256) {
        unsigned int w = tmp_tgt[i];
        int tl = (int)(w >> 17);
        int src = (int)(w & 0x1FFFF);
        int pos = beg + atomicAdd(&hist[tl], 1);
        edges[pos] = src;
    }
}

// ---------------- linear layer 1: h1 = fp16(X @ W1 + b1) ----------------
// BR=64 rows/block (1563 blocks), KC=32 K-chunks, register-prefetch pipeline,
// nontemporal X loads. LDS ~10.5 KB; __launch_bounds__ caps VGPR for occupancy.

__global__ __launch_bounds__(256, 4)
void linear1_kernel(const float* __restrict__ x, const float* __restrict__ w1,
                    const float* __restrict__ b1, __half* __restrict__ h1h, int n) {
    __shared__ float xs[KC][BR + 2];   // [32][66] = 8.4 KB
    __shared__ float wsc[KC * HID];    // 2 KB
    __shared__ float bl[HID];
    int t = threadIdx.x;
    if (t < HID) bl[t] = b1[t];
    int row0 = blockIdx.x * BR;
    int rp = t >> 2;            // 0..63 -> row
    int cq = (t & 3) * 4;       // channel quad
    float acc[4] = {0, 0, 0, 0};

    // prefetch registers: 2 float4 of X + 2 floats of W per thread
    fv4 xp[2];
    float wp[2];
    int rr_[2], kk_[2];
#pragma unroll
    for (int u = 0; u < 2; ++u) {
        int i = t + u * 256;
        rr_[u] = i >> 3;            // row in tile (0..63)
        kk_[u] = (i & 7) * 4;       // k within chunk
    }
    auto prefetch = [&](int kc) {
#pragma unroll
        for (int u = 0; u < 2; ++u) {
            int grow = row0 + rr_[u];
            if (grow < n) {
                xp[u] = __builtin_nontemporal_load((const fv4*)(x + (size_t)grow * FIN + kc + kk_[u]));
            } else {
                xp[u] = (fv4){0.f, 0.f, 0.f, 0.f};
            }
        }
        wp[0] = w1[kc * HID + t];
        wp[1] = w1[kc * HID + t + 256];
    };

    prefetch(0);
    for (int kc = 0; kc < FIN; kc += KC) {
        __syncthreads();   // previous compute done before overwriting LDS
#pragma unroll
        for (int u = 0; u < 2; ++u) {
            xs[kk_[u] + 0][rr_[u]] = xp[u].x;
            xs[kk_[u] + 1][rr_[u]] = xp[u].y;
            xs[kk_[u] + 2][rr_[u]] = xp[u].z;
            xs[kk_[u] + 3][rr_[u]] = xp[u].w;
        }
        wsc[t] = wp[0];
        wsc[t + 256] = wp[1];
        __syncthreads();
        if (kc + KC < FIN) prefetch(kc + KC);   // overlap with compute below
#pragma unroll 8
        for (int k = 0; k < KC; ++k) {
            float xv = xs[k][rp];
            float4 wv = *(const float4*)&wsc[k * HID + cq];
            acc[0] = fmaf(xv, wv.x, acc[0]);
            acc[1] = fmaf(xv, wv.y, acc[1]);
            acc[2] = fmaf(xv, wv.z, acc[2]);
            acc[3] = fmaf(xv, wv.w, acc[3]);
        }
    }
    int r0 = row0 + rp;
    if (r0 < n) {
        __half2* hp = (__half2*)(h1h + (size_t)r0 * HID + cq);
        hp[0] = __floats2half2_rn(acc[0] + bl[cq + 0], acc[1] + bl[cq + 1]);
        hp[1] = __floats2half2_rn(acc[2] + bl[cq + 2], acc[3] + bl[cq + 3]);
    }
}

// ---------------- agg1: 32 threads/node (4 edge-strides x 8 channel-pairs) ----------------
// out[t][c] = relu( dinv[t]^2*in[t][c] + sum_e dinv[src]*dinv[t]*in[src][c] )

__global__ void agg1_kernel(const __half* __restrict__ in, const int* __restrict__ edges,
                            const int* __restrict__ row_ptr, const float* __restrict__ dinv,
                            __half* __restrict__ out16, float* __restrict__ rowsum, int n) {
    int gid = blockIdx.x * blockDim.x + threadIdx.x;
    int node = gid >> 5;
    int sub = (gid >> 3) & 3;
    int c2 = gid & 7;
    if (node >= n) return;
    const __half2* tab = (const __half2*)in;
    float dv = dinv[node];
    float a0 = 0.f, a1 = 0.f, rs = 0.f;
    if (sub == 0) {
        float self = dv * dv;
        float2 sv = __half22float2(tab[(size_t)node * 8 + c2]);
        a0 = self * sv.x; a1 = self * sv.y; rs = self;
    }
    int beg = row_ptr[node], end = row_ptr[node + 1];
#pragma unroll 4
    for (int i = beg + sub; i < end; i += 4) {
        int src = edges[i];
        float nrm = dinv[src] * dv;
        float2 v = __half22float2(tab[(size_t)src * 8 + c2]);
        a0 = fmaf(nrm, v.x, a0);
        a1 = fmaf(nrm, v.y, a1);
        rs += nrm;
    }
    a0 += __shfl_xor(a0, 8);  a1 += __shfl_xor(a1, 8);  rs += __shfl_xor(rs, 8);
    a0 += __shfl_xor(a0, 16); a1 += __shfl_xor(a1, 16); rs += __shfl_xor(rs, 16);
    if (sub == 0) {
        a0 = fmaxf(a0, 0.f); a1 = fmaxf(a1, 0.f);
        ((__half2*)out16)[(size_t)node * 8 + c2] = __floats2half2_rn(a0, a1);
        if (c2 == 0) rowsum[node] = rs;
    }
}

// ---------------- agg2 + final fused: out = log_softmax((A g) W2 + rowsum*b2) ----------
// 256 threads = 8 nodes x 32 threads; aggregated features staged through LDS,
// epilogue (40-ch linear + log_softmax) on 2 threads/node.

__global__ void agg2_kernel(const __half* __restrict__ in, const int* __restrict__ edges,
                            const int* __restrict__ row_ptr, const float* __restrict__ dinv,
                            const float* __restrict__ rowsum,
                            const float* __restrict__ w2, const float* __restrict__ b2,
                            float* __restrict__ out, int n) {
    __shared__ float g2[8][HID + 1];
    __shared__ float wl[HID * NCLS];
    __shared__ float bl[NCLS];
    int t = threadIdx.x;
    for (int i = t; i < HID * NCLS; i += 256) wl[i] = w2[i];
    if (t < NCLS) bl[t] = b2[t];
    int gid = blockIdx.x * 256 + t;
    int node = gid >> 5;
    int sub = (t >> 3) & 3;
    int c2 = t & 7;
    int nl = t >> 5;
    float a0 = 0.f, a1 = 0.f;
    if (node < n) {
        const __half2* tab = (const __half2*)in;
        float dv = dinv[node];
        if (sub == 0) {
            float self = dv * dv;
            float2 sv = __half22float2(tab[(size_t)node * 8 + c2]);
            a0 = self * sv.x; a1 = self * sv.y;
        }
        int beg = row_ptr[node], end = row_ptr[node + 1];
#pragma unroll 4
        for (int i = beg + sub; i < end; i += 4) {
            int src = edges[i];
            float nrm = dinv[src] * dv;
            float2 v = __half22float2(tab[(size_t)src * 8 + c2]);
            a0 = fmaf(nrm, v.x, a0);
            a1 = fmaf(nrm, v.y, a1);
        }
    }
    a0 += __shfl_xor(a0, 8);  a1 += __shfl_xor(a1, 8);
    a0 += __shfl_xor(a0, 16); a1 += __shfl_xor(a1, 16);
    if (sub == 0) { g2[nl][c2 * 2] = a0; g2[nl][c2 * 2 + 1] = a1; }
    __syncthreads();
    if (t < 16) {
        int nl2 = t >> 1, half = t & 1;
        int node2 = blockIdx.x * 8 + nl2;
        float z[20];
        float m = -1e30f, se = 0.f;
        if (node2 < n) {
            float h[HID];
#pragma unroll
            for (int j = 0; j < HID; ++j) h[j] = g2[nl2][j];
            float rs = rowsum[node2];
            int c0 = half * 20;
#pragma unroll
            for (int c = 0; c < 20; ++c) {
                float s = rs * bl[c0 + c];
#pragma unroll
                for (int j = 0; j < HID; ++j) s = fmaf(h[j], wl[j * NCLS + c0 + c], s);
                z[c] = s;
            }
            m = z[0];
#pragma unroll
            for (int c = 1; c < 20; ++c) m = fmaxf(m, z[c]);
        }
        m = fmaxf(m, __shfl_xor(m, 1));
        if (node2 < n) {
#pragma unroll
            for (int c = 0; c < 20; ++c) se += __expf(z[c] - m);
        }
        se += __shfl_xor(se, 1);
        if (node2 < n) {
            float lse = m + __logf(se);
            float* orow = out + (size_t)node2 * NCLS + half * 20;
#pragma unroll
            for (int c = 0; c < 20; ++c) orow[c] = z[c] - lse;
        }
    }
}

// ---------------- launch ----------------

extern "C" void kernel_launch(void* const* d_in, const int* in_sizes, int n_in,
                              void* d_out, int out_size, void* d_ws, size_t ws_size,
                              hipStream_t stream) {
    const float* x  = (const float*)d_in[0];
    const int*   ei = (const int*)d_in[1];
    const float* w1 = (const float*)d_in[2];
    const float* b1 = (const float*)d_in[3];
    const float* w2 = (const float*)d_in[4];
    const float* b2 = (const float*)d_in[5];
    float* out = (float*)d_out;

    int N = in_sizes[0] / FIN;     // 100000
    int E = in_sizes[1] / 2;       // 3200000
    int nb = (N + 255) >> SHIFT;   // 391 coarse buckets (<= NBCAP)

    char* p = (char*)d_ws;
    auto alloc = [&](size_t bytes) -> char* {
        char* r = p;
        p += (bytes + 255) / 256 * 256;
        return r;
    };
    int*   hist_src_g = (int*)alloc((size_t)NBLK * NBCAP * 4);   // 1 MB
    int*   hist_tgt_g = (int*)alloc((size_t)NBLK * NBCAP * 4);   // 1 MB
    int*   btot       = (int*)alloc((size_t)2 * NBCAP * 4);
    int*   src_base   = (int*)alloc((size_t)(nb + 1) * 4);
    int*   tgt_base   = (int*)alloc((size_t)(nb + 1) * 4);
    float* dinv       = (float*)alloc((size_t)N * 4);
    int*   row_ptr    = (int*)alloc((size_t)(N + 1) * 4);
    unsigned char* tmp_src = (unsigned char*)alloc((size_t)E);       // 3.2 MB
    unsigned int*  tmp_tgt = (unsigned int*)alloc((size_t)E * 4);    // 12.8 MB
    int*    edges     = (int*)alloc((size_t)E * 4);                  // 12.8 MB
    __half* h1h       = (__half*)alloc((size_t)N * HID * 2);         // 3.2 MB
    __half* gh        = (__half*)alloc((size_t)N * HID * 2);         // 3.2 MB
    float*  rowsum    = (float*)alloc((size_t)N * 4);

    count_kernel<<<NBLK, 256, 0, stream>>>(ei, E, nb, hist_src_g, hist_tgt_g);
    colscan_kernel<<<dim3(nb, 2), NBLK, 0, stream>>>(hist_src_g, hist_tgt_g, btot);
    bucketscan_kernel<<<1, 512, 0, stream>>>(btot, nb, src_base, tgt_base, row_ptr, N, E);
    scatter_kernel<<<NBLK, 256, 0, stream>>>(ei, E, nb, hist_src_g, hist_tgt_g,
                                             src_base, tgt_base, tmp_src, tmp_tgt);
    fine_kernel<<<nb, 256, 0, stream>>>(tmp_src, src_base, tmp_tgt, tgt_base,
                                        dinv, row_ptr, edges, N);
    linear1_kernel<<<(N + BR - 1) / BR, 256, 0, stream>>>(x, w1, b1, h1h, N);
    agg1_kernel<<<(N * 32 + 255) / 256, 256, 0, stream>>>(h1h, edges, row_ptr, dinv,
                                                          gh, rowsum, N);
    agg2_kernel<<<(N * 32 + 255) / 256, 256, 0, stream>>>(gh, edges, row_ptr, dinv,
                                                          rowsum, w2, b2, out, N);
}